// Round 21
// baseline (114.000 us; speedup 1.0000x reference)
//
#include <hip/hip_runtime.h>

typedef _Float16 half8 __attribute__((ext_vector_type(8)));
typedef _Float16 half4v __attribute__((ext_vector_type(4)));
typedef __fp16 fp16x2 __attribute__((ext_vector_type(2)));
typedef float f32x4 __attribute__((ext_vector_type(4)));
typedef float f32x16 __attribute__((ext_vector_type(16)));
typedef float float4v __attribute__((ext_vector_type(4)));
typedef unsigned uint32x2 __attribute__((ext_vector_type(2)));

constexpr int NS = 4096;   // B*S rows
constexpr int E  = 1024;
constexpr int H  = 16;
constexpr int HD = 64;
constexpr int M  = 2048;
constexpr int HE = 1024;   // H*HD

__device__ __forceinline__ void gload16(const _Float16* g, _Float16* l) {
  __builtin_amdgcn_global_load_lds((__attribute__((address_space(1))) void*)g,
                                   (__attribute__((address_space(3))) void*)l, 16, 0, 0);
}

__device__ __forceinline__ float fexp2(float x) {
#if __has_builtin(__builtin_amdgcn_exp2f)
  return __builtin_amdgcn_exp2f(x);
#else
  return __expf(x * 0.6931471805599453f);
#endif
}

// pack two f32 -> one dword of 2 fp16 (RTZ)
__device__ __forceinline__ unsigned pkh(float a, float b) {
  fp16x2 t = __builtin_amdgcn_cvt_pkrtz(a, b);
  return __builtin_bit_cast(unsigned, t);
}

// lane<->lane+32 half-exchange
__device__ __forceinline__ uint32x2 pl32swap(unsigned a, unsigned b) {
#if __has_builtin(__builtin_amdgcn_permlane32_swap)
  return __builtin_amdgcn_permlane32_swap(a, b, false, false);
#else
  unsigned sa = (unsigned)__shfl_xor((int)a, 32, 64);
  unsigned sb = (unsigned)__shfl_xor((int)b, 32, 64);
  uint32x2 r;
  r.x = (threadIdx.x & 32) ? sb : a;
  r.y = (threadIdx.x & 32) ? b : sa;
  return r;
#endif
}

__device__ __forceinline__ half8 mk8(unsigned a, unsigned b, unsigned c, unsigned d) {
  union { unsigned u[4]; half8 h; } t;
  t.u[0] = a; t.u[1] = b; t.u[2] = c; t.u[3] = d;
  return t.h;
}

// ---------------- prep mega-kernel (r19-proven) ----------------

__global__ void prep_all(const float* __restrict__ tensor, _Float16* __restrict__ th,
                         const float* __restrict__ Kp, _Float16* __restrict__ Khb,
                         const float* __restrict__ Wq, _Float16* __restrict__ Wqt,
                         const float* __restrict__ Wd, _Float16* __restrict__ Wdt,
                         const float* __restrict__ Vp, _Float16* __restrict__ Vth) {
  __shared__ float tile[32][33];
  const int b = blockIdx.x;
  const int tid = threadIdx.x;

  if (b < 6144) {
    const float* in;
    _Float16* out;
    float scale;
    int i;
    if (b < 4096) {
      in = tensor; out = th; scale = 1.0f;
      i = (b * 256 + tid) * 4;
    } else {
      in = Kp; out = Khb; scale = 1.44269504088896f;
      i = ((b - 4096) * 256 + tid) * 4;
    }
    float4v v = *(const float4v*)(in + i);
    half4v o = { (_Float16)(v[0] * scale), (_Float16)(v[1] * scale),
                 (_Float16)(v[2] * scale), (_Float16)(v[3] * scale) };
    *(half4v*)(out + i) = o;
    return;
  }

  const int tx = tid & 31, ty = tid >> 5;  // 32 x 8
  if (b < 8192) {
    const int lb = b - 6144;
    const float* in = (lb >> 10) ? Wd : Wq;
    _Float16* out = (lb >> 10) ? Wdt : Wqt;
    const int rem = lb & 1023;
    const int c0 = (rem & 31) * 32, r0 = (rem >> 5) * 32;
#pragma unroll
    for (int i = 0; i < 4; ++i)
      tile[ty + 8 * i][tx] = in[(size_t)(r0 + ty + 8 * i) * 1024 + c0 + tx];
    __syncthreads();
#pragma unroll
    for (int i = 0; i < 4; ++i)
      out[(size_t)(c0 + ty + 8 * i) * 1024 + r0 + tx] = (_Float16)tile[tx][ty + 8 * i];
    return;
  }

  {
    const int lb = b - 8192;
    const int z = lb >> 7;             // head
    const int rem = lb & 127;
    const int c0 = (rem & 1) * 32;     // col-tile over C=64
    const int r0 = (rem >> 1) * 32;    // row-tile over R=2048
    const float* in = Vp + (size_t)z * 2048 * 64;
    _Float16* out = Vth + (size_t)z * 2048 * 64;
#pragma unroll
    for (int i = 0; i < 4; ++i)
      tile[ty + 8 * i][tx] = in[(size_t)(r0 + ty + 8 * i) * 64 + c0 + tx];
    __syncthreads();
#pragma unroll
    for (int i = 0; i < 4; ++i)
      out[(size_t)(c0 + ty + 8 * i) * 2048 + r0 + tx] = (_Float16)tile[tx][ty + 8 * i];
  }
}

// ---------------- GEMM: C[M][N] = A[M][K] * Bt[N][K]^T, fp32 acc ----------------
// (r20-proven) BK=64: two 32-k halves per barrier round. LDS 48 KB, grid 512.

template <typename OUT_T>
__global__ __launch_bounds__(256, 4) void gemm_f16(
    const _Float16* __restrict__ A,   // [Mrows][K]
    const _Float16* __restrict__ Bt,  // [Ncols][K]
    const float* __restrict__ bias,   // [Ncols]
    OUT_T* __restrict__ C,            // [Mrows][Ncols]
    int Ncols, int K, float scale)
{
  __shared__ alignas(16) _Float16 Ab[2][2][8 * 512];  // 32 KB: [buf][khalf][chunk]
  __shared__ alignas(16) _Float16 Bb[2][2][4 * 512];  // 16 KB
  const int tid = threadIdx.x;
  const int wave = tid >> 6, lane = tid & 63;
  const int l15 = lane & 15, l4 = lane >> 4;

  const int nwg = gridDim.x;
  int wg = (blockIdx.x & 7) * (nwg >> 3) + (blockIdx.x >> 3);  // XCD swizzle (nwg%8==0)
  const int nbn = Ncols >> 6;
  const int mblk = wg / nbn, nblk = wg % nbn;

  const _Float16* aS0 = A  + (size_t)(mblk * 128 + wave * 16 + l15) * K + l4 * 8;
  const _Float16* aS1 = aS0 + (size_t)64 * K;
  const _Float16* bS  = Bt + (size_t)(nblk * 64 + wave * 16 + l15) * K + l4 * 8;

  const int wr = wave >> 1, wc = wave & 1;  // 2x2 wave grid, wave tile 64x32
  f32x4 acc[4][2];
#pragma unroll
  for (int i = 0; i < 4; ++i)
#pragma unroll
    for (int n = 0; n < 2; ++n) acc[i][n] = (f32x4){0.f, 0.f, 0.f, 0.f};

#define GSTAGE(b, kk) {                                    \
    gload16(aS0 + (kk),      &Ab[b][0][wave * 512]);       \
    gload16(aS0 + (kk) + 32, &Ab[b][1][wave * 512]);       \
    gload16(aS1 + (kk),      &Ab[b][0][(wave + 4) * 512]); \
    gload16(aS1 + (kk) + 32, &Ab[b][1][(wave + 4) * 512]); \
    gload16(bS + (kk),       &Bb[b][0][wave * 512]);       \
    gload16(bS + (kk) + 32,  &Bb[b][1][wave * 512]); }

  GSTAGE(0, 0);
  const int nk = K >> 6;
  for (int kt = 0; kt < nk; ++kt) {
    __syncthreads();   // own tile-kt loads drained + all waves' loads visible
    if (kt + 1 < nk) GSTAGE((kt + 1) & 1, (kt + 1) * 64);
    const int buf = kt & 1;
#pragma unroll
    for (int s = 0; s < 2; ++s) {
      const _Float16* Ac = &Ab[buf][s][0];
      const _Float16* Bc = &Bb[buf][s][0];
      half8 af[4], bf[2];
#pragma unroll
      for (int i = 0; i < 4; ++i) af[i] = *(const half8*)(Ac + (wr * 4 + i) * 512 + lane * 8);
#pragma unroll
      for (int n = 0; n < 2; ++n) bf[n] = *(const half8*)(Bc + (wc * 2 + n) * 512 + lane * 8);
      __builtin_amdgcn_s_setprio(1);
#pragma unroll
      for (int i = 0; i < 4; ++i)
#pragma unroll
        for (int n = 0; n < 2; ++n)
          acc[i][n] = __builtin_amdgcn_mfma_f32_16x16x32_f16(af[i], bf[n], acc[i][n], 0, 0, 0);
      __builtin_amdgcn_s_setprio(0);
    }
  }
#undef GSTAGE

  const int row0 = mblk * 128 + wr * 64;
  const int col0 = nblk * 64 + wc * 32;
#pragma unroll
  for (int n = 0; n < 2; ++n) {
    int col = col0 + n * 16 + l15;
    float bv = bias[col];
#pragma unroll
    for (int i = 0; i < 4; ++i)
#pragma unroll
      for (int r = 0; r < 4; ++r) {
        int row = row0 + i * 16 + l4 * 4 + r;
        C[(size_t)row * Ncols + col] = (OUT_T)(acc[i][n][r] * scale + bv);
      }
  }
}

// ---------------- fused attention (M-split x2, 64 q/wave, in-register P) --------
// r13 structure with the two m-subtiles processed SEQUENTIALLY (each: QK ->
// exp/pack/swap -> PV with its own V chunks), reusing kf/s/pa registers across
// subtiles. Same LDS traffic / MFMA count / accumulation order as r13; peak
// register liveness drops ~32-48 (target: arch VGPR <= ~106 so total with
// 64 acc-AGPRs crosses the 3-waves/SIMD threshold of 170). No bounds change.

__global__ __launch_bounds__(256, 2) void attn_fused(
    const _Float16* __restrict__ qh,    // [NS][HE]
    const _Float16* __restrict__ Kh,    // [H][M][HD]  (pre-scaled by log2 e)
    const _Float16* __restrict__ Vth,   // [H][HD][M]
    _Float16* __restrict__ Op0,         // [NS][HE] partial sum pV, half 0
    _Float16* __restrict__ Op1,         // [NS][HE] partial sum pV, half 1
    float* __restrict__ Spart)          // [2][NS][H] partial sum p
{
  __shared__ alignas(16) _Float16 Kb[2][4096];  // 16 KB: 2 subtiles x (32m x 64d)
  __shared__ alignas(16) _Float16 Vb[2][4096];  // 16 KB: 2 subtiles x (64d x 32m)

  int wg = (blockIdx.x & 7) * 64 + (blockIdx.x >> 3);  // 2 heads per XCD
  const int h = wg >> 5, half = (wg >> 4) & 1, qblk = wg & 15;
  const int m0 = half * 1024;
  const int tid = threadIdx.x;
  const int wave = tid >> 6, lane = tid & 63;
  const int l31 = lane & 31, hi = lane >> 5;
  const int s0 = qblk * 256 + wave * 64;

  // Q B-frags for both q-groups: lane holds Q[s0+g*32+l31][c*16 + hi*8 + j]
  half8 qf[2][4];
#pragma unroll
  for (int g = 0; g < 2; ++g) {
    const _Float16* qp = qh + (size_t)(s0 + g * 32 + l31) * HE + h * HD + hi * 8;
    qf[g][0] = *(const half8*)(qp);
    qf[g][1] = *(const half8*)(qp + 16);
    qf[g][2] = *(const half8*)(qp + 32);
    qf[g][3] = *(const half8*)(qp + 48);
  }

  const _Float16* kS = Kh + (size_t)h * M * HD
                       + (size_t)((wave >> 1) * 32 + l31) * HD + (wave & 1) * 32 + hi * 8;
  const _Float16* vS = Vth + (size_t)(h * HD + (wave & 1) * 32 + l31) * M
                       + (wave >> 1) * 32 + hi * 8;
  const int dOff = wave * 1024 + lane * 8;

  f32x16 accA[2], accB[2];
  float lsum[2] = {0.f, 0.f};
#pragma unroll
  for (int g = 0; g < 2; ++g) {
    accA[g] = (f32x16){0.f,0.f,0.f,0.f,0.f,0.f,0.f,0.f,0.f,0.f,0.f,0.f,0.f,0.f,0.f,0.f};
    accB[g] = (f32x16){0.f,0.f,0.f,0.f,0.f,0.f,0.f,0.f,0.f,0.f,0.f,0.f,0.f,0.f,0.f,0.f};
  }

#define STAGE(b, mm) {                                        \
    gload16(kS + (size_t)(mm) * HD,      &Kb[b][dOff]);       \
    gload16(kS + (size_t)(mm) * HD + 16, &Kb[b][dOff + 512]); \
    gload16(vS + (mm),                   &Vb[b][dOff]);       \
    gload16(vS + (mm) + 16,              &Vb[b][dOff + 512]); }

// One 32-m subtile: QK (K chunks KB..KB+3) -> exp/pack/permlane -> PV
// (V chunks KB..KB+3). All state local; registers reused across invocations.
#define SUBTILE(KB) {                                                                   \
    half8 kf0 = *(const half8*)(Kc + (KB + 0) * 512 + lane * 8);                        \
    half8 kf1 = *(const half8*)(Kc + (KB + 1) * 512 + lane * 8);                        \
    half8 kf2 = *(const half8*)(Kc + (KB + 2) * 512 + lane * 8);                        \
    half8 kf3 = *(const half8*)(Kc + (KB + 3) * 512 + lane * 8);                        \
    half8 pa0[2], pa1[2];                                                               \
    _Pragma("unroll")                                                                   \
    for (int g = 0; g < 2; ++g) {                                                       \
      f32x16 s = (f32x16){0.f,0.f,0.f,0.f,0.f,0.f,0.f,0.f,0.f,0.f,0.f,0.f,0.f,0.f,0.f,0.f}; \
      __builtin_amdgcn_s_setprio(1);                                                    \
      s = __builtin_amdgcn_mfma_f32_32x32x16_f16(kf0, qf[g][0], s, 0, 0, 0);            \
      s = __builtin_amdgcn_mfma_f32_32x32x16_f16(kf1, qf[g][1], s, 0, 0, 0);            \
      s = __builtin_amdgcn_mfma_f32_32x32x16_f16(kf2, qf[g][2], s, 0, 0, 0);            \
      s = __builtin_amdgcn_mfma_f32_32x32x16_f16(kf3, qf[g][3], s, 0, 0, 0);            \
      __builtin_amdgcn_s_setprio(0);                                                    \
      unsigned pd[8];                                                                   \
      float la = 0.f;                                                                   \
      _Pragma("unroll")                                                                 \
      for (int i = 0; i < 8; ++i) {                                                     \
        float a0 = fexp2(s[2 * i]);                                                     \
        float a1 = fexp2(s[2 * i + 1]);                                                 \
        la += a0 + a1;                                                                  \
        pd[i] = pkh(a0, a1);                                                            \
      }                                                                                 \
      lsum[g] += la;                                                                    \
      uint32x2 w0 = pl32swap(pd[0], pd[2]);                                             \
      uint32x2 w1 = pl32swap(pd[1], pd[3]);                                             \
      uint32x2 w2 = pl32swap(pd[4], pd[6]);                                             \
      uint32x2 w3 = pl32swap(pd[5], pd[7]);                                             \
      pa0[g] = mk8(w0.x, w1.x, w0.y, w1.y);                                             \
      pa1[g] = mk8(w2.x, w3.x, w2.y, w3.y);                                             \
    }                                                                                   \
    half8 v0 = *(const half8*)(Vc + (KB + 0) * 512 + lane * 8);                         \
    half8 v1 = *(const half8*)(Vc + (KB + 1) * 512 + lane * 8);                         \
    half8 v2 = *(const half8*)(Vc + (KB + 2) * 512 + lane * 8);                         \
    half8 v3 = *(const half8*)(Vc + (KB + 3) * 512 + lane * 8);                         \
    __builtin_amdgcn_s_setprio(1);                                                      \
    _Pragma("unroll")                                                                   \
    for (int g = 0; g < 2; ++g) {                                                       \
      accA[g] = __builtin_amdgcn_mfma_f32_32x32x16_f16(pa0[g], v0, accA[g], 0, 0, 0);   \
      accA[g] = __builtin_amdgcn_mfma_f32_32x32x16_f16(pa1[g], v1, accA[g], 0, 0, 0);   \
      accB[g] = __builtin_amdgcn_mfma_f32_32x32x16_f16(pa0[g], v2, accB[g], 0, 0, 0);   \
      accB[g] = __builtin_amdgcn_mfma_f32_32x32x16_f16(pa1[g], v3, accB[g], 0, 0, 0);   \
    }                                                                                   \
    __builtin_amdgcn_s_setprio(0);                                                      \
  }

  STAGE(0, m0);
  for (int kt = 0; kt < 16; ++kt) {
    const int cur = kt & 1;
    __syncthreads();   // own tile-kt loads drained + all waves' loads visible
    if (kt < 15) STAGE(cur ^ 1, m0 + (kt + 1) * 64);

    const _Float16* Kc = &Kb[cur][0];
    const _Float16* Vc = &Vb[cur][0];
    SUBTILE(0);   // m 0..31 of this 64-m tile
    SUBTILE(4);   // m 32..63
  }
#undef STAGE
#undef SUBTILE

  _Float16* Op = half ? Op1 : Op0;
  float* Sp = Spart + (size_t)half * (NS * H);
#pragma unroll
  for (int g = 0; g < 2; ++g) {
#pragma unroll
    for (int r = 0; r < 16; ++r) {
      int q = s0 + g * 32 + (r & 3) + 8 * (r >> 2) + 4 * hi;
      Op[(size_t)q * HE + h * HD + l31]      = (_Float16)accA[g][r];
      Op[(size_t)q * HE + h * HD + 32 + l31] = (_Float16)accB[g][r];
    }
    float tot = lsum[g] + __shfl_xor(lsum[g], 32, 64);
    if (hi == 0) Sp[(size_t)(s0 + g * 32 + l31) * H + h] = tot;
  }
}

// combine: attnh = (O0 + O1) / (S0 + S1)
__global__ void attn_combine(const _Float16* __restrict__ O0, const _Float16* __restrict__ O1,
                             const float* __restrict__ Spart, _Float16* __restrict__ out) {
  int idx = (blockIdx.x * 256 + threadIdx.x) * 8;
  int row = idx >> 10, he = idx & 1023, h = he >> 6;
  half8 a = *(const half8*)(O0 + idx);
  half8 b = *(const half8*)(O1 + idx);
  float s = Spart[(size_t)row * H + h] + Spart[(size_t)(NS + row) * H + h];
  float inv = 1.0f / s;
  half8 o;
#pragma unroll
  for (int j = 0; j < 8; ++j) o[j] = (_Float16)(((float)a[j] + (float)b[j]) * inv);
  *(half8*)(out + idx) = o;
}

// ---------------- launch ----------------

extern "C" void kernel_launch(void* const* d_in, const int* in_sizes, int n_in,
                              void* d_out, int out_size, void* d_ws, size_t ws_size,
                              hipStream_t stream) {
  const float* tensor = (const float*)d_in[0];
  const float* Wq     = (const float*)d_in[1];
  const float* bq     = (const float*)d_in[2];
  const float* Kp     = (const float*)d_in[3];
  const float* Vp     = (const float*)d_in[4];
  const float* Wd     = (const float*)d_in[5];
  const float* bd     = (const float*)d_in[6];
  float* out = (float*)d_out;

  char* ws = (char*)d_ws;
  _Float16* th    = (_Float16*)(ws);                  // [4096][1024] 8 MB; reused as Op0
  _Float16* qhb   = (_Float16*)(ws + (8  << 20));     // 8 MB
  _Float16* attnh = (_Float16*)(ws + (16 << 20));     // 8 MB
  _Float16* Wqt   = (_Float16*)(ws + (24 << 20));     // 2 MB; reused as Spart after gemm1
  _Float16* Wdt   = (_Float16*)(ws + (26 << 20));     // 2 MB
  _Float16* Khb   = (_Float16*)(ws + (28 << 20));     // 4 MB
  _Float16* Vth   = (_Float16*)(ws + (32 << 20));     // 4 MB
  _Float16* Op0   = (_Float16*)(ws);                  // overlays th (dead after gemm1)
  _Float16* Op1   = (_Float16*)(ws + (36 << 20));     // 8 MB  (total 44 MB)
  float*    Spart = (float*)(ws + (24 << 20));        // [2][4096][16] f32, overlays Wqt

  prep_all<<<10240, 256, 0, stream>>>(tensor, th, Kp, Khb, Wq, Wqt, Wd, Wdt, Vp, Vth);

  gemm_f16<_Float16><<<512, 256, 0, stream>>>(th, Wqt, bq, qhb, HE, E, 1.0f);
  attn_fused<<<512, 256, 0, stream>>>(qhb, Khb, Vth, Op0, Op1, Spart);
  attn_combine<<<(NS * HE) / 2048, 256, 0, stream>>>(Op0, Op1, Spart, attnh);
  gemm_f16<float><<<512, 256, 0, stream>>>(attnh, Wdt, bd, out, E, HE, 0.125f);
}

// Round 22
// 113.841 us; speedup vs baseline: 1.0014x; 1.0014x over previous
//
#include <hip/hip_runtime.h>

typedef _Float16 half8 __attribute__((ext_vector_type(8)));
typedef _Float16 half4v __attribute__((ext_vector_type(4)));
typedef __fp16 fp16x2 __attribute__((ext_vector_type(2)));
typedef float f32x4 __attribute__((ext_vector_type(4)));
typedef float f32x16 __attribute__((ext_vector_type(16)));
typedef float float4v __attribute__((ext_vector_type(4)));
typedef unsigned uint32x2 __attribute__((ext_vector_type(2)));

constexpr int NS = 4096;   // B*S rows
constexpr int E  = 1024;
constexpr int H  = 16;
constexpr int HD = 64;
constexpr int M  = 2048;
constexpr int HE = 1024;   // H*HD

__device__ __forceinline__ void gload16(const _Float16* g, _Float16* l) {
  __builtin_amdgcn_global_load_lds((__attribute__((address_space(1))) void*)g,
                                   (__attribute__((address_space(3))) void*)l, 16, 0, 0);
}

__device__ __forceinline__ float fexp2(float x) {
#if __has_builtin(__builtin_amdgcn_exp2f)
  return __builtin_amdgcn_exp2f(x);
#else
  return __expf(x * 0.6931471805599453f);
#endif
}

// pack two f32 -> one dword of 2 fp16 (RTZ)
__device__ __forceinline__ unsigned pkh(float a, float b) {
  fp16x2 t = __builtin_amdgcn_cvt_pkrtz(a, b);
  return __builtin_bit_cast(unsigned, t);
}

// lane<->lane+32 half-exchange
__device__ __forceinline__ uint32x2 pl32swap(unsigned a, unsigned b) {
#if __has_builtin(__builtin_amdgcn_permlane32_swap)
  return __builtin_amdgcn_permlane32_swap(a, b, false, false);
#else
  unsigned sa = (unsigned)__shfl_xor((int)a, 32, 64);
  unsigned sb = (unsigned)__shfl_xor((int)b, 32, 64);
  uint32x2 r;
  r.x = (threadIdx.x & 32) ? sb : a;
  r.y = (threadIdx.x & 32) ? b : sa;
  return r;
#endif
}

__device__ __forceinline__ half8 mk8(unsigned a, unsigned b, unsigned c, unsigned d) {
  union { unsigned u[4]; half8 h; } t;
  t.u[0] = a; t.u[1] = b; t.u[2] = c; t.u[3] = d;
  return t.h;
}

// ---------------- prep mega-kernel (r19-proven) ----------------

__global__ void prep_all(const float* __restrict__ tensor, _Float16* __restrict__ th,
                         const float* __restrict__ Kp, _Float16* __restrict__ Khb,
                         const float* __restrict__ Wq, _Float16* __restrict__ Wqt,
                         const float* __restrict__ Wd, _Float16* __restrict__ Wdt,
                         const float* __restrict__ Vp, _Float16* __restrict__ Vth) {
  __shared__ float tile[32][33];
  const int b = blockIdx.x;
  const int tid = threadIdx.x;

  if (b < 6144) {
    const float* in;
    _Float16* out;
    float scale;
    int i;
    if (b < 4096) {
      in = tensor; out = th; scale = 1.0f;
      i = (b * 256 + tid) * 4;
    } else {
      in = Kp; out = Khb; scale = 1.44269504088896f;
      i = ((b - 4096) * 256 + tid) * 4;
    }
    float4v v = *(const float4v*)(in + i);
    half4v o = { (_Float16)(v[0] * scale), (_Float16)(v[1] * scale),
                 (_Float16)(v[2] * scale), (_Float16)(v[3] * scale) };
    *(half4v*)(out + i) = o;
    return;
  }

  const int tx = tid & 31, ty = tid >> 5;  // 32 x 8
  if (b < 8192) {
    const int lb = b - 6144;
    const float* in = (lb >> 10) ? Wd : Wq;
    _Float16* out = (lb >> 10) ? Wdt : Wqt;
    const int rem = lb & 1023;
    const int c0 = (rem & 31) * 32, r0 = (rem >> 5) * 32;
#pragma unroll
    for (int i = 0; i < 4; ++i)
      tile[ty + 8 * i][tx] = in[(size_t)(r0 + ty + 8 * i) * 1024 + c0 + tx];
    __syncthreads();
#pragma unroll
    for (int i = 0; i < 4; ++i)
      out[(size_t)(c0 + ty + 8 * i) * 1024 + r0 + tx] = (_Float16)tile[tx][ty + 8 * i];
    return;
  }

  {
    const int lb = b - 8192;
    const int z = lb >> 7;             // head
    const int rem = lb & 127;
    const int c0 = (rem & 1) * 32;     // col-tile over C=64
    const int r0 = (rem >> 1) * 32;    // row-tile over R=2048
    const float* in = Vp + (size_t)z * 2048 * 64;
    _Float16* out = Vth + (size_t)z * 2048 * 64;
#pragma unroll
    for (int i = 0; i < 4; ++i)
      tile[ty + 8 * i][tx] = in[(size_t)(r0 + ty + 8 * i) * 64 + c0 + tx];
    __syncthreads();
#pragma unroll
    for (int i = 0; i < 4; ++i)
      out[(size_t)(c0 + ty + 8 * i) * 2048 + r0 + tx] = (_Float16)tile[tx][ty + 8 * i];
  }
}

// ---------------- GEMM: C[M][N] = A[M][K] * Bt[N][K]^T, fp32 acc ----------------
// (r20-proven) BK=64: two 32-k halves per barrier round. LDS 48 KB, grid 512.

template <typename OUT_T>
__global__ __launch_bounds__(256, 4) void gemm_f16(
    const _Float16* __restrict__ A,   // [Mrows][K]
    const _Float16* __restrict__ Bt,  // [Ncols][K]
    const float* __restrict__ bias,   // [Ncols]
    OUT_T* __restrict__ C,            // [Mrows][Ncols]
    int Ncols, int K, float scale)
{
  __shared__ alignas(16) _Float16 Ab[2][2][8 * 512];  // 32 KB: [buf][khalf][chunk]
  __shared__ alignas(16) _Float16 Bb[2][2][4 * 512];  // 16 KB
  const int tid = threadIdx.x;
  const int wave = tid >> 6, lane = tid & 63;
  const int l15 = lane & 15, l4 = lane >> 4;

  const int nwg = gridDim.x;
  int wg = (blockIdx.x & 7) * (nwg >> 3) + (blockIdx.x >> 3);  // XCD swizzle (nwg%8==0)
  const int nbn = Ncols >> 6;
  const int mblk = wg / nbn, nblk = wg % nbn;

  const _Float16* aS0 = A  + (size_t)(mblk * 128 + wave * 16 + l15) * K + l4 * 8;
  const _Float16* aS1 = aS0 + (size_t)64 * K;
  const _Float16* bS  = Bt + (size_t)(nblk * 64 + wave * 16 + l15) * K + l4 * 8;

  const int wr = wave >> 1, wc = wave & 1;  // 2x2 wave grid, wave tile 64x32
  f32x4 acc[4][2];
#pragma unroll
  for (int i = 0; i < 4; ++i)
#pragma unroll
    for (int n = 0; n < 2; ++n) acc[i][n] = (f32x4){0.f, 0.f, 0.f, 0.f};

#define GSTAGE(b, kk) {                                    \
    gload16(aS0 + (kk),      &Ab[b][0][wave * 512]);       \
    gload16(aS0 + (kk) + 32, &Ab[b][1][wave * 512]);       \
    gload16(aS1 + (kk),      &Ab[b][0][(wave + 4) * 512]); \
    gload16(aS1 + (kk) + 32, &Ab[b][1][(wave + 4) * 512]); \
    gload16(bS + (kk),       &Bb[b][0][wave * 512]);       \
    gload16(bS + (kk) + 32,  &Bb[b][1][wave * 512]); }

  GSTAGE(0, 0);
  const int nk = K >> 6;
  for (int kt = 0; kt < nk; ++kt) {
    __syncthreads();   // own tile-kt loads drained + all waves' loads visible
    if (kt + 1 < nk) GSTAGE((kt + 1) & 1, (kt + 1) * 64);
    const int buf = kt & 1;
#pragma unroll
    for (int s = 0; s < 2; ++s) {
      const _Float16* Ac = &Ab[buf][s][0];
      const _Float16* Bc = &Bb[buf][s][0];
      half8 af[4], bf[2];
#pragma unroll
      for (int i = 0; i < 4; ++i) af[i] = *(const half8*)(Ac + (wr * 4 + i) * 512 + lane * 8);
#pragma unroll
      for (int n = 0; n < 2; ++n) bf[n] = *(const half8*)(Bc + (wc * 2 + n) * 512 + lane * 8);
      __builtin_amdgcn_s_setprio(1);
#pragma unroll
      for (int i = 0; i < 4; ++i)
#pragma unroll
        for (int n = 0; n < 2; ++n)
          acc[i][n] = __builtin_amdgcn_mfma_f32_16x16x32_f16(af[i], bf[n], acc[i][n], 0, 0, 0);
      __builtin_amdgcn_s_setprio(0);
    }
  }
#undef GSTAGE

  const int row0 = mblk * 128 + wr * 64;
  const int col0 = nblk * 64 + wc * 32;
#pragma unroll
  for (int n = 0; n < 2; ++n) {
    int col = col0 + n * 16 + l15;
    float bv = bias[col];
#pragma unroll
    for (int i = 0; i < 4; ++i)
#pragma unroll
      for (int r = 0; r < 4; ++r) {
        int row = row0 + i * 16 + l4 * 4 + r;
        C[(size_t)row * Ncols + col] = (OUT_T)(acc[i][n][r] * scale + bv);
      }
  }
}

// ---------------- fused attention (M-split x2, 64 q/wave, in-register P) --------
// (byte-identical to r13/r16/r20 — best measured ~52 us; frozen)

__global__ __launch_bounds__(256, 2) void attn_fused(
    const _Float16* __restrict__ qh,    // [NS][HE]
    const _Float16* __restrict__ Kh,    // [H][M][HD]  (pre-scaled by log2 e)
    const _Float16* __restrict__ Vth,   // [H][HD][M]
    _Float16* __restrict__ Op0,         // [NS][HE] partial sum pV, half 0
    _Float16* __restrict__ Op1,         // [NS][HE] partial sum pV, half 1
    float* __restrict__ Spart)          // [2][NS][H] partial sum p
{
  __shared__ alignas(16) _Float16 Kb[2][4096];  // 16 KB: 2 subtiles x (32m x 64d)
  __shared__ alignas(16) _Float16 Vb[2][4096];  // 16 KB: 2 subtiles x (64d x 32m)

  int wg = (blockIdx.x & 7) * 64 + (blockIdx.x >> 3);  // 2 heads per XCD
  const int h = wg >> 5, half = (wg >> 4) & 1, qblk = wg & 15;
  const int m0 = half * 1024;
  const int tid = threadIdx.x;
  const int wave = tid >> 6, lane = tid & 63;
  const int l31 = lane & 31, hi = lane >> 5;
  const int s0 = qblk * 256 + wave * 64;

  // Q B-frags for both q-groups: lane holds Q[s0+g*32+l31][c*16 + hi*8 + j]
  half8 qf[2][4];
#pragma unroll
  for (int g = 0; g < 2; ++g) {
    const _Float16* qp = qh + (size_t)(s0 + g * 32 + l31) * HE + h * HD + hi * 8;
    qf[g][0] = *(const half8*)(qp);
    qf[g][1] = *(const half8*)(qp + 16);
    qf[g][2] = *(const half8*)(qp + 32);
    qf[g][3] = *(const half8*)(qp + 48);
  }

  const _Float16* kS = Kh + (size_t)h * M * HD
                       + (size_t)((wave >> 1) * 32 + l31) * HD + (wave & 1) * 32 + hi * 8;
  const _Float16* vS = Vth + (size_t)(h * HD + (wave & 1) * 32 + l31) * M
                       + (wave >> 1) * 32 + hi * 8;
  const int dOff = wave * 1024 + lane * 8;

  f32x16 accA[2], accB[2];
  float lsum[2] = {0.f, 0.f};
#pragma unroll
  for (int g = 0; g < 2; ++g) {
    accA[g] = (f32x16){0.f,0.f,0.f,0.f,0.f,0.f,0.f,0.f,0.f,0.f,0.f,0.f,0.f,0.f,0.f,0.f};
    accB[g] = (f32x16){0.f,0.f,0.f,0.f,0.f,0.f,0.f,0.f,0.f,0.f,0.f,0.f,0.f,0.f,0.f,0.f};
  }

#define STAGE(b, mm) {                                        \
    gload16(kS + (size_t)(mm) * HD,      &Kb[b][dOff]);       \
    gload16(kS + (size_t)(mm) * HD + 16, &Kb[b][dOff + 512]); \
    gload16(vS + (mm),                   &Vb[b][dOff]);       \
    gload16(vS + (mm) + 16,              &Vb[b][dOff + 512]); }

  STAGE(0, m0);
  for (int kt = 0; kt < 16; ++kt) {
    const int cur = kt & 1;
    __syncthreads();   // own tile-kt loads drained + all waves' loads visible
    if (kt < 15) STAGE(cur ^ 1, m0 + (kt + 1) * 64);

    const _Float16* Kc = &Kb[cur][0];
    const _Float16* Vc = &Vb[cur][0];
    half8 kf[8];
#pragma unroll
    for (int c = 0; c < 8; ++c) kf[c] = *(const half8*)(Kc + c * 512 + lane * 8);

    half8 paA0[2], paA1[2], paB0[2], paB1[2];
#pragma unroll
    for (int g = 0; g < 2; ++g) {
      f32x16 sA = (f32x16){0.f,0.f,0.f,0.f,0.f,0.f,0.f,0.f,0.f,0.f,0.f,0.f,0.f,0.f,0.f,0.f};
      f32x16 sB = sA;
      __builtin_amdgcn_s_setprio(1);
#pragma unroll
      for (int c = 0; c < 4; ++c)
        sA = __builtin_amdgcn_mfma_f32_32x32x16_f16(kf[c], qf[g][c], sA, 0, 0, 0);
#pragma unroll
      for (int c = 0; c < 4; ++c)
        sB = __builtin_amdgcn_mfma_f32_32x32x16_f16(kf[4 + c], qf[g][c], sB, 0, 0, 0);
      __builtin_amdgcn_s_setprio(0);

      unsigned pdA[8], pdB[8];
      float la = 0.f;
#pragma unroll
      for (int i = 0; i < 8; ++i) {
        float a0 = fexp2(sA[2 * i]);
        float a1 = fexp2(sA[2 * i + 1]);
        float b0 = fexp2(sB[2 * i]);
        float b1 = fexp2(sB[2 * i + 1]);
        la += (a0 + a1) + (b0 + b1);
        pdA[i] = pkh(a0, a1);
        pdB[i] = pkh(b0, b1);
      }
      lsum[g] += la;
      uint32x2 wA0 = pl32swap(pdA[0], pdA[2]);
      uint32x2 wA1 = pl32swap(pdA[1], pdA[3]);
      uint32x2 wA2 = pl32swap(pdA[4], pdA[6]);
      uint32x2 wA3 = pl32swap(pdA[5], pdA[7]);
      paA0[g] = mk8(wA0.x, wA1.x, wA0.y, wA1.y);
      paA1[g] = mk8(wA2.x, wA3.x, wA2.y, wA3.y);
      uint32x2 wB0 = pl32swap(pdB[0], pdB[2]);
      uint32x2 wB1 = pl32swap(pdB[1], pdB[3]);
      uint32x2 wB2 = pl32swap(pdB[4], pdB[6]);
      uint32x2 wB3 = pl32swap(pdB[5], pdB[7]);
      paB0[g] = mk8(wB0.x, wB1.x, wB0.y, wB1.y);
      paB1[g] = mk8(wB2.x, wB3.x, wB2.y, wB3.y);
    }

    // PV: V chunks read once, used by both q-groups
    {
      half8 v0 = *(const half8*)(Vc + lane * 8);
      half8 v1 = *(const half8*)(Vc + 512 + lane * 8);
      half8 v2 = *(const half8*)(Vc + 1024 + lane * 8);
      half8 v3 = *(const half8*)(Vc + 1536 + lane * 8);
      __builtin_amdgcn_s_setprio(1);
#pragma unroll
      for (int g = 0; g < 2; ++g) {
        accA[g] = __builtin_amdgcn_mfma_f32_32x32x16_f16(paA0[g], v0, accA[g], 0, 0, 0);
        accA[g] = __builtin_amdgcn_mfma_f32_32x32x16_f16(paA1[g], v1, accA[g], 0, 0, 0);
        accB[g] = __builtin_amdgcn_mfma_f32_32x32x16_f16(paA0[g], v2, accB[g], 0, 0, 0);
        accB[g] = __builtin_amdgcn_mfma_f32_32x32x16_f16(paA1[g], v3, accB[g], 0, 0, 0);
      }
      __builtin_amdgcn_s_setprio(0);
    }
    {
      half8 v0 = *(const half8*)(Vc + 2048 + lane * 8);
      half8 v1 = *(const half8*)(Vc + 2560 + lane * 8);
      half8 v2 = *(const half8*)(Vc + 3072 + lane * 8);
      half8 v3 = *(const half8*)(Vc + 3584 + lane * 8);
      __builtin_amdgcn_s_setprio(1);
#pragma unroll
      for (int g = 0; g < 2; ++g) {
        accA[g] = __builtin_amdgcn_mfma_f32_32x32x16_f16(paB0[g], v0, accA[g], 0, 0, 0);
        accA[g] = __builtin_amdgcn_mfma_f32_32x32x16_f16(paB1[g], v1, accA[g], 0, 0, 0);
        accB[g] = __builtin_amdgcn_mfma_f32_32x32x16_f16(paB0[g], v2, accB[g], 0, 0, 0);
        accB[g] = __builtin_amdgcn_mfma_f32_32x32x16_f16(paB1[g], v3, accB[g], 0, 0, 0);
      }
      __builtin_amdgcn_s_setprio(0);
    }
  }
#undef STAGE

  _Float16* Op = half ? Op1 : Op0;
  float* Sp = Spart + (size_t)half * (NS * H);
#pragma unroll
  for (int g = 0; g < 2; ++g) {
#pragma unroll
    for (int r = 0; r < 16; ++r) {
      int q = s0 + g * 32 + (r & 3) + 8 * (r >> 2) + 4 * hi;
      Op[(size_t)q * HE + h * HD + l31]      = (_Float16)accA[g][r];
      Op[(size_t)q * HE + h * HD + 32 + l31] = (_Float16)accB[g][r];
    }
    float tot = lsum[g] + __shfl_xor(lsum[g], 32, 64);
    if (hi == 0) Sp[(size_t)(s0 + g * 32 + l31) * H + h] = tot;
  }
}

// combine: attnh = (O0 + O1) / (S0 + S1)
__global__ void attn_combine(const _Float16* __restrict__ O0, const _Float16* __restrict__ O1,
                             const float* __restrict__ Spart, _Float16* __restrict__ out) {
  int idx = (blockIdx.x * 256 + threadIdx.x) * 8;
  int row = idx >> 10, he = idx & 1023, h = he >> 6;
  half8 a = *(const half8*)(O0 + idx);
  half8 b = *(const half8*)(O1 + idx);
  float s = Spart[(size_t)row * H + h] + Spart[(size_t)(NS + row) * H + h];
  float inv = 1.0f / s;
  half8 o;
#pragma unroll
  for (int j = 0; j < 8; ++j) o[j] = (_Float16)(((float)a[j] + (float)b[j]) * inv);
  *(half8*)(out + idx) = o;
}

// ---------------- launch ----------------

extern "C" void kernel_launch(void* const* d_in, const int* in_sizes, int n_in,
                              void* d_out, int out_size, void* d_ws, size_t ws_size,
                              hipStream_t stream) {
  const float* tensor = (const float*)d_in[0];
  const float* Wq     = (const float*)d_in[1];
  const float* bq     = (const float*)d_in[2];
  const float* Kp     = (const float*)d_in[3];
  const float* Vp     = (const float*)d_in[4];
  const float* Wd     = (const float*)d_in[5];
  const float* bd     = (const float*)d_in[6];
  float* out = (float*)d_out;

  char* ws = (char*)d_ws;
  _Float16* th    = (_Float16*)(ws);                  // [4096][1024] 8 MB; reused as Op0
  _Float16* qhb   = (_Float16*)(ws + (8  << 20));     // 8 MB
  _Float16* attnh = (_Float16*)(ws + (16 << 20));     // 8 MB
  _Float16* Wqt   = (_Float16*)(ws + (24 << 20));     // 2 MB; reused as Spart after gemm1
  _Float16* Wdt   = (_Float16*)(ws + (26 << 20));     // 2 MB
  _Float16* Khb   = (_Float16*)(ws + (28 << 20));     // 4 MB
  _Float16* Vth   = (_Float16*)(ws + (32 << 20));     // 4 MB
  _Float16* Op0   = (_Float16*)(ws);                  // overlays th (dead after gemm1)
  _Float16* Op1   = (_Float16*)(ws + (36 << 20));     // 8 MB  (total 44 MB)
  float*    Spart = (float*)(ws + (24 << 20));        // [2][4096][16] f32, overlays Wqt

  prep_all<<<10240, 256, 0, stream>>>(tensor, th, Kp, Khb, Wq, Wqt, Wd, Wdt, Vp, Vth);

  gemm_f16<_Float16><<<512, 256, 0, stream>>>(th, Wqt, bq, qhb, HE, E, 1.0f);
  attn_fused<<<512, 256, 0, stream>>>(qhb, Khb, Vth, Op0, Op1, Spart);
  attn_combine<<<(NS * HE) / 2048, 256, 0, stream>>>(Op0, Op1, Spart, attnh);
  gemm_f16<float><<<512, 256, 0, stream>>>(attnh, Wdt, bd, out, E, HE, 0.125f);
}